// Round 17
// baseline (1118.071 us; speedup 1.0000x reference)
//
#include <hip/hip_runtime.h>

// ROUND 17: OUTPUT IS FLOAT32 (proven by r16 oracle: u16 writes invisible in
// f32 read; out_npz 3.89MB = 1M f32). Original semantics restored:
// x [B,S,E] contiguous rows b*2048+s, dict-order (x,Wq,Wk,Wv), W [1024][64]
// k-major, causal over S per batch, scale 1/8, out [B,S,D] float.
// Pipeline = audited r4 VALU structure, f32 end-to-end.
// ws: WtF f32[192][1024] (768 KB) | qkvF f32[2048][192] (1.5 MB slab per b)

#define BATCH 8
#define SEQ   2048
#define EMB   1024
#define HD    64
#define QKVLD 192

typedef __attribute__((ext_vector_type(4))) float f32x4;

// ---------------------------------------------------------------------------
// Kernel 1: transpose Wq|Wk|Wv f32[1024][64] -> WtF f32[192][1024]
// ---------------------------------------------------------------------------
__global__ __launch_bounds__(256) void transpose_w_f32(
    const float* __restrict__ Wq, const float* __restrict__ Wk,
    const float* __restrict__ Wv, float* __restrict__ WtF) {
    __shared__ float tileT[64][68];
    int bid = blockIdx.x;
    int p = bid >> 4, kt = bid & 15;
    const float* W = (p == 0) ? Wq : ((p == 1) ? Wk : Wv);
    int t = threadIdx.x;
    int k0 = kt * 64;
    int row = t >> 2, c0 = (t & 3) * 16;
    const float* src = W + (long)(k0 + row) * HD + c0;
    #pragma unroll
    for (int j = 0; j < 16; ++j) tileT[c0 + j][row] = src[j];
    __syncthreads();
    int n = t >> 2, ks = (t & 3) * 16;
    float* dst = WtF + (long)(p * 64 + n) * EMB + k0 + ks;
    #pragma unroll
    for (int j = 0; j < 16; ++j) dst[j] = tileT[n][ks + j];
}

// ---------------------------------------------------------------------------
// Kernel 2 (VALU): qkvF[s][c] = sum_k x[b*2048 + s][k] * WtF[c][k], f32.
// ---------------------------------------------------------------------------
__global__ __launch_bounds__(256) void proj_valu(
    const float* __restrict__ x, const float* __restrict__ WtF,
    float* __restrict__ qkv, int m_base) {
    __shared__ float xL[16][67];
    __shared__ float wL[192][67];
    int t = threadIdx.x;
    int m0 = blockIdx.x * 16;
    int rp = t >> 5;
    int cg = t & 31;
    int r0 = rp * 2, c0 = cg * 6;

    float acc[2][6];
    #pragma unroll
    for (int i = 0; i < 2; ++i)
        #pragma unroll
        for (int j = 0; j < 6; ++j) acc[i][j] = 0.f;

    for (int k0 = 0; k0 < EMB; k0 += 64) {
        __syncthreads();
        {   // stage x chunk 16x64 f32 (contiguous rows)
            int row = t >> 4, seg = (t & 15) * 4;
            const float* s = x + (long)(m_base + m0 + row) * EMB + k0 + seg;
            #pragma unroll
            for (int j = 0; j < 4; ++j) xL[row][seg + j] = s[j];
        }
        #pragma unroll
        for (int j = 0; j < 12; ++j) {   // stage W chunk 192x64 f32
            int idx = j * 256 + t;
            int c = idx >> 4, seg = (idx & 15) * 4;
            const float* s = WtF + (long)c * EMB + k0 + seg;
            f32x4 v = *(const f32x4*)s;
            wL[c][seg] = v[0]; wL[c][seg + 1] = v[1];
            wL[c][seg + 2] = v[2]; wL[c][seg + 3] = v[3];
        }
        __syncthreads();
        #pragma unroll 4
        for (int k = 0; k < 64; ++k) {
            float a0 = xL[r0][k], a1 = xL[r0 + 1][k];
            #pragma unroll
            for (int j = 0; j < 6; ++j) {
                float b2 = wL[c0 + j][k];
                acc[0][j] += a0 * b2;
                acc[1][j] += a1 * b2;
            }
        }
    }
    #pragma unroll
    for (int i = 0; i < 2; ++i)
        #pragma unroll
        for (int j = 0; j < 6; ++j)
            qkv[(long)(m0 + r0 + i) * QKVLD + c0 + j] = acc[i][j];
}

// ---------------------------------------------------------------------------
// Kernel 3 (VALU): CAUSAL flash attention over s; OUTPUT = FLOAT, [B,S,D].
// ---------------------------------------------------------------------------
__global__ __launch_bounds__(256) void attn_causal(
    const float* __restrict__ qkv, float* __restrict__ out, int b) {
    __shared__ float xq[4][65];
    __shared__ float KL[64][65];
    __shared__ float VL[64][65];
    __shared__ float PL[4][64];

    int qt = (SEQ / 4 - 1) - blockIdx.x;   // heavy tiles first
    int q0 = qt * 4;
    int t = threadIdx.x;
    int w = t >> 6, l = t & 63;

    const float cs = 0.125f * 1.44269504088896f;  // 1/sqrt(64) * log2(e)

    {   // stage 4 q-rows, pre-scaled into log2 domain
        int row = t >> 6, d = t & 63;
        xq[row][d] = qkv[(long)(q0 + row) * QKVLD + d] * cs;
    }

    int q = q0 + w;
    float m = -1e30f, lsum = 0.f, accd = 0.f;   // lane l -> out[.][d=l]
    int nch = q0 / 64 + 1;

    for (int c = 0; c < nch; ++c) {
        int kv0 = c * 64;
        __syncthreads();
        #pragma unroll
        for (int j = 0; j < 16; ++j) {   // stage K,V chunk 64x64 each
            int idx = j * 256 + t;
            int row = idx >> 6, d = idx & 63;
            KL[row][d] = qkv[(long)(kv0 + row) * QKVLD + HD + d];
            VL[row][d] = qkv[(long)(kv0 + row) * QKVLD + 2 * HD + d];
        }
        __syncthreads();

        float s = 0.f;
        #pragma unroll 8
        for (int d = 0; d < 64; ++d)
            s += xq[w][d] * KL[l][d];
        bool active = (kv0 + l) <= q;
        s = active ? s : -1e30f;

        float tm = s;
        #pragma unroll
        for (int off = 1; off < 64; off <<= 1)
            tm = fmaxf(tm, __shfl_xor(tm, off, 64));
        float mnew = fmaxf(m, tm);
        float fac = __builtin_amdgcn_exp2f(m - mnew);   // first iter -> 0
        float p = __builtin_amdgcn_exp2f(s - mnew);     // masked -> 0
        float ps = p;
        #pragma unroll
        for (int off = 1; off < 64; off <<= 1)
            ps += __shfl_xor(ps, off, 64);
        lsum = lsum * fac + ps;
        m = mnew;

        PL[w][l] = p;   // same-wave LDS write->read: in-order
        float a = accd * fac;
        #pragma unroll 8
        for (int k = 0; k < 64; ++k)
            a += PL[w][k] * VL[k][l];
        accd = a;
    }

    // FLOAT output, [B, S, D]
    out[(long)b * SEQ * HD + (long)q * HD + l] = accd / lsum;
}

// ---------------------------------------------------------------------------
extern "C" void kernel_launch(void* const* d_in, const int* in_sizes, int n_in,
                              void* d_out, int out_size, void* d_ws, size_t ws_size,
                              hipStream_t stream) {
    const float* x  = (const float*)d_in[0];
    const float* Wq = (const float*)d_in[1];
    const float* Wk = (const float*)d_in[2];
    const float* Wv = (const float*)d_in[3];
    float* outp = (float*)d_out;

    float* WtF  = (float*)d_ws;                           // 768 KB
    float* qkvF = (float*)((char*)d_ws + 786432);         // 1.5 MB slab

    transpose_w_f32<<<48, 256, 0, stream>>>(Wq, Wk, Wv, WtF);

    for (int b = 0; b < BATCH; ++b) {
        proj_valu<<<SEQ / 16, 256, 0, stream>>>(x, WtF, qkvF, b * SEQ);
        attn_causal<<<SEQ / 4, 256, 0, stream>>>(qkvF, outp, b);
    }
}

// Round 18
// 166.781 us; speedup vs baseline: 6.7038x; 6.7038x over previous
//
#include <hip/hip_runtime.h>

// ROUND 18: MFMA pipeline under the PROVEN contract (r17):
// inputs f32 dict-order (x,Wq,Wk,Wv), W [1024][64] k-major, causal over S
// per batch, scale 1/8, OUTPUT FLOAT32 [B,S,D].
// 3 launches: W transpose->bf16 | MFMA proj (all batches) | MFMA attn (grid y=8).
// ws: Wt bf16[192][1024] (384 KB) | qkv bf16[16384][192] (6.29 MB) = 6.68 MB.

#define BATCH 8
#define SEQ   2048
#define EMB   1024
#define HD    64
#define QKVLD 192

typedef __attribute__((ext_vector_type(8))) short short8;
typedef __attribute__((ext_vector_type(4))) float f32x4;

static __device__ __forceinline__ short f2bf(float f) {
    union { float f; unsigned int i; } c;
    c.f = f;
    unsigned int r = c.i + 0x7fff + ((c.i >> 16) & 1);  // RNE
    return (short)(r >> 16);
}

// ---------------------------------------------------------------------------
// Kernel 1: transpose+convert Wq|Wk|Wv f32[1024][64] -> Wt bf16[192][1024]
// ---------------------------------------------------------------------------
__global__ __launch_bounds__(256) void transpose_w(
    const float* __restrict__ Wq, const float* __restrict__ Wk,
    const float* __restrict__ Wv, short* __restrict__ Wt) {
    __shared__ short tileT[64][72];
    int bid = blockIdx.x;
    int p = bid >> 4, kt = bid & 15;
    const float* W = (p == 0) ? Wq : ((p == 1) ? Wk : Wv);
    int t = threadIdx.x;
    int k0 = kt * 64;
    int row = t >> 2, c0 = (t & 3) * 16;
    const float* src = W + (long)(k0 + row) * HD + c0;
    #pragma unroll
    for (int j = 0; j < 16; ++j)
        tileT[c0 + j][row] = f2bf(src[j]);
    __syncthreads();
    int n = t >> 2, ks = (t & 3) * 16;
    short8 o0 = *(const short8*)(&tileT[n][ks]);
    short8 o1 = *(const short8*)(&tileT[n][ks + 8]);
    *(short8*)(Wt + (long)(p * 64 + n) * EMB + k0 + ks)     = o0;
    *(short8*)(Wt + (long)(p * 64 + n) * EMB + k0 + ks + 8) = o1;
}

// ---------------------------------------------------------------------------
// Kernel 2: MFMA projection GEMM  qkv[m][n] = x[m][k] * Wt[n][k]^T
// M=16384, N=192, K=1024. BM=64, BN=192, BK=64. 512 thr = 8 waves (2x4).
// grid 256 blocks. x f32 -> bf16 during staging.
// ---------------------------------------------------------------------------
__global__ __launch_bounds__(512) void proj_mfma(
    const float* __restrict__ x, const short* __restrict__ Wt,
    short* __restrict__ qkv) {
    __shared__ short xL[64][72];
    __shared__ short wL[192][72];
    int t = threadIdx.x;
    int m0 = blockIdx.x * 64;
    int w = t >> 6, l = t & 63;
    int wr = w >> 2, wc = w & 3;
    int ll = l & 15, lg = l >> 4;

    f32x4 acc[2][3] = {};

    int arow = wr * 32 + ll;
    int brow = wc * 48 + ll;
    int kcol = lg * 8;

    for (int k0 = 0; k0 < EMB; k0 += 64) {
        __syncthreads();
        {   // stage x tile 64x64: f32 -> bf16, 8 elems/thread
            int row = t >> 3, c8 = (t & 7) * 8;
            const float* src = x + (long)(m0 + row) * EMB + k0 + c8;
            f32x4 a = *(const f32x4*)(src);
            f32x4 b = *(const f32x4*)(src + 4);
            short8 v;
            #pragma unroll
            for (int j = 0; j < 4; ++j) { v[j] = f2bf(a[j]); v[4 + j] = f2bf(b[j]); }
            *(short8*)(&xL[row][c8]) = v;
        }
        #pragma unroll
        for (int c = 0; c < 3; ++c) {   // stage W tile 192x64 (bf16)
            int idx = c * 512 + t;
            int n = idx >> 3, c8 = idx & 7;
            short8 v = *(const short8*)(Wt + (long)n * EMB + k0 + c8 * 8);
            *(short8*)(&wL[n][c8 * 8]) = v;
        }
        __syncthreads();
        #pragma unroll
        for (int ks = 0; ks < 2; ++ks) {
            short8 af[2], bf[3];
            #pragma unroll
            for (int mi = 0; mi < 2; ++mi)
                af[mi] = *(const short8*)(&xL[arow + mi * 16][kcol + ks * 32]);
            #pragma unroll
            for (int ni = 0; ni < 3; ++ni)
                bf[ni] = *(const short8*)(&wL[brow + ni * 16][kcol + ks * 32]);
            #pragma unroll
            for (int mi = 0; mi < 2; ++mi)
                #pragma unroll
                for (int ni = 0; ni < 3; ++ni)
                    acc[mi][ni] = __builtin_amdgcn_mfma_f32_16x16x32_bf16(
                        af[mi], bf[ni], acc[mi][ni], 0, 0, 0);
        }
    }
    // epilogue: C/D layout col = lane&15, row = (lane>>4)*4 + reg
    int orow = m0 + wr * 32 + lg * 4;
    int ocol = wc * 48 + ll;
    #pragma unroll
    for (int mi = 0; mi < 2; ++mi)
        #pragma unroll
        for (int ni = 0; ni < 3; ++ni)
            #pragma unroll
            for (int r = 0; r < 4; ++r)
                qkv[(long)(orow + mi * 16 + r) * QKVLD + ocol + ni * 16] =
                    f2bf(acc[mi][ni][r]);
}

// ---------------------------------------------------------------------------
// Kernel 3: MFMA causal flash attention. QBLK=32 (2 waves x 16 q-rows),
// KVB=64. grid (64 heavy-first, 8), 128 thr. qkv bf16 in, f32 out [B,S,D].
// ---------------------------------------------------------------------------
#define QBLK 32
#define KVB  64

__global__ __launch_bounds__(128) void attn_mfma(
    const short* __restrict__ qkv, float* __restrict__ out) {
    __shared__ short KL[64][72];
    __shared__ short VT[64][72];
    __shared__ short PL[2][16][72];

    int b = blockIdx.y;
    int qt = (SEQ / QBLK - 1) - blockIdx.x;
    int q0 = qt * QBLK;
    int t = threadIdx.x;
    int w = t >> 6, l = t & 63;
    int lg = l >> 4, ll = l & 15;

    const short* base = qkv + (long)b * SEQ * QKVLD;

    short8 qf[2];
    #pragma unroll
    for (int ks = 0; ks < 2; ++ks)
        qf[ks] = *(const short8*)(base + (long)(q0 + w * 16 + ll) * QKVLD + ks * 32 + lg * 8);

    f32x4 accO[4] = {};
    float mrow[4], lrow[4];
    #pragma unroll
    for (int r = 0; r < 4; ++r) { mrow[r] = -1e30f; lrow[r] = 0.f; }

    const float cs = 0.125f * 1.44269504088896f;
    int nkv = (q0 + QBLK + KVB - 1) / KVB;

    for (int kt = 0; kt < nkv; ++kt) {
        int kv0 = kt * KVB;
        __syncthreads();
        #pragma unroll
        for (int c = 0; c < 4; ++c) {   // stage K 64x64
            int idx = c * 128 + t;
            int row = idx >> 3, c8 = idx & 7;
            short8 v = *(const short8*)(base + (long)(kv0 + row) * QKVLD + HD + c8 * 8);
            *(short8*)(&KL[row][c8 * 8]) = v;
        }
        #pragma unroll
        for (int c = 0; c < 4; ++c) {   // stage V transposed
            int idx = c * 128 + t;
            int row = idx >> 3, c8 = idx & 7;
            short8 v = *(const short8*)(base + (long)(kv0 + row) * QKVLD + 2 * HD + c8 * 8);
            #pragma unroll
            for (int j = 0; j < 8; ++j) VT[c8 * 8 + j][row] = v[j];
        }
        __syncthreads();

        // S = Q K^T
        f32x4 s[4] = {};
        #pragma unroll
        for (int ks = 0; ks < 2; ++ks)
            #pragma unroll
            for (int n = 0; n < 4; ++n) {
                short8 kf = *(const short8*)(&KL[n * 16 + ll][ks * 32 + lg * 8]);
                s[n] = __builtin_amdgcn_mfma_f32_16x16x32_bf16(qf[ks], kf, s[n], 0, 0, 0);
            }

        // scale + causal mask + online softmax (row = lg*4+r, col = n*16+ll)
        bool need_mask = (kv0 + KVB - 1) > q0;
        int qrow_base = q0 + w * 16 + lg * 4;
        float sm[4][4], tmax[4];
        #pragma unroll
        for (int r = 0; r < 4; ++r) tmax[r] = -1e30f;
        #pragma unroll
        for (int n = 0; n < 4; ++n) {
            int kvcol = kv0 + n * 16 + ll;
            #pragma unroll
            for (int r = 0; r < 4; ++r) {
                float v = s[n][r] * cs;
                if (need_mask && (kvcol > qrow_base + r)) v = -1e30f;
                sm[n][r] = v;
                tmax[r] = fmaxf(tmax[r], v);
            }
        }
        #pragma unroll
        for (int off = 1; off < 16; off <<= 1)
            #pragma unroll
            for (int r = 0; r < 4; ++r)
                tmax[r] = fmaxf(tmax[r], __shfl_xor(tmax[r], off, 64));

        float fac[4], psum[4];
        #pragma unroll
        for (int r = 0; r < 4; ++r) {
            float mnew = fmaxf(mrow[r], tmax[r]);
            fac[r] = __builtin_amdgcn_exp2f(mrow[r] - mnew);
            mrow[r] = mnew;
            psum[r] = 0.f;
        }
        #pragma unroll
        for (int n = 0; n < 4; ++n)
            #pragma unroll
            for (int r = 0; r < 4; ++r) {
                float p = __builtin_amdgcn_exp2f(sm[n][r] - mrow[r]);
                sm[n][r] = p;
                psum[r] += p;
            }
        #pragma unroll
        for (int off = 1; off < 16; off <<= 1)
            #pragma unroll
            for (int r = 0; r < 4; ++r)
                psum[r] += __shfl_xor(psum[r], off, 64);
        #pragma unroll
        for (int r = 0; r < 4; ++r) lrow[r] = lrow[r] * fac[r] + psum[r];
        #pragma unroll
        for (int n = 0; n < 4; ++n)
            #pragma unroll
            for (int r = 0; r < 4; ++r) accO[n][r] *= fac[r];

        // P -> LDS (wave-local, same-wave r/w validated by r17), PV MFMAs
        #pragma unroll
        for (int n = 0; n < 4; ++n)
            #pragma unroll
            for (int r = 0; r < 4; ++r)
                PL[w][lg * 4 + r][n * 16 + ll] = f2bf(sm[n][r]);

        #pragma unroll
        for (int ks = 0; ks < 2; ++ks) {
            short8 pf = *(const short8*)(&PL[w][ll][ks * 32 + lg * 8]);
            #pragma unroll
            for (int nd = 0; nd < 4; ++nd) {
                short8 vf = *(const short8*)(&VT[nd * 16 + ll][ks * 32 + lg * 8]);
                accO[nd] = __builtin_amdgcn_mfma_f32_16x16x32_bf16(pf, vf, accO[nd], 0, 0, 0);
            }
        }
    }

    // epilogue: f32 output [B,S,D]
    #pragma unroll
    for (int r = 0; r < 4; ++r) {
        float inv = 1.0f / lrow[r];
        #pragma unroll
        for (int nd = 0; nd < 4; ++nd)
            out[(long)b * SEQ * HD + (long)(q0 + w * 16 + lg * 4 + r) * HD + nd * 16 + ll]
                = accO[nd][r] * inv;
    }
}

// ---------------------------------------------------------------------------
extern "C" void kernel_launch(void* const* d_in, const int* in_sizes, int n_in,
                              void* d_out, int out_size, void* d_ws, size_t ws_size,
                              hipStream_t stream) {
    const float* x  = (const float*)d_in[0];
    const float* Wq = (const float*)d_in[1];
    const float* Wk = (const float*)d_in[2];
    const float* Wv = (const float*)d_in[3];
    float* outp = (float*)d_out;

    short* Wt  = (short*)d_ws;                       // bf16 [192][1024]
    short* qkv = (short*)d_ws + 3 * HD * EMB;        // bf16 [16384][192]

    transpose_w<<<48, 256, 0, stream>>>(Wq, Wk, Wv, Wt);
    proj_mfma<<<BATCH * SEQ / 64, 512, 0, stream>>>(x, Wt, qkv);
    dim3 ag(SEQ / QBLK, BATCH);
    attn_mfma<<<ag, 128, 0, stream>>>(qkv, outp);
}

// Round 19
// 144.148 us; speedup vs baseline: 7.7564x; 1.1570x over previous
//
#include <hip/hip_runtime.h>

// ROUND 19: attention without LDS staging (K/V L2-resident, direct global
// MFMA-fragment loads), V pre-transposed by proj. 1-wave attn blocks,
// QBLK=16, grid (128,8), no barriers. Contract (proven r17): f32 inputs
// dict-order, W [1024][64] k-major, causal/S per batch, scale 1/8, f32 out [B,S,D].
// ws: Wt bf16[192][1024] 384KB | qg bf16[16384][64] 2MB | kg 2MB | vtg[8][64][2048] 2MB

#define BATCH 8
#define SEQ   2048
#define EMB   1024
#define HD    64

typedef __attribute__((ext_vector_type(8))) short short8;
typedef __attribute__((ext_vector_type(4))) float f32x4;

static __device__ __forceinline__ short f2bf(float f) {
    union { float f; unsigned int i; } c;
    c.f = f;
    unsigned int r = c.i + 0x7fff + ((c.i >> 16) & 1);  // RNE
    return (short)(r >> 16);
}

// ---------------------------------------------------------------------------
// Kernel 1: transpose+convert Wq|Wk|Wv f32[1024][64] -> Wt bf16[192][1024]
// ---------------------------------------------------------------------------
__global__ __launch_bounds__(256) void transpose_w(
    const float* __restrict__ Wq, const float* __restrict__ Wk,
    const float* __restrict__ Wv, short* __restrict__ Wt) {
    __shared__ short tileT[64][72];
    int bid = blockIdx.x;
    int p = bid >> 4, kt = bid & 15;
    const float* W = (p == 0) ? Wq : ((p == 1) ? Wk : Wv);
    int t = threadIdx.x;
    int k0 = kt * 64;
    int row = t >> 2, c0 = (t & 3) * 16;
    const float* src = W + (long)(k0 + row) * HD + c0;
    #pragma unroll
    for (int j = 0; j < 16; ++j)
        tileT[c0 + j][row] = f2bf(src[j]);
    __syncthreads();
    int n = t >> 2, ks = (t & 3) * 16;
    short8 o0 = *(const short8*)(&tileT[n][ks]);
    short8 o1 = *(const short8*)(&tileT[n][ks + 8]);
    *(short8*)(Wt + (long)(p * 64 + n) * EMB + k0 + ks)     = o0;
    *(short8*)(Wt + (long)(p * 64 + n) * EMB + k0 + ks + 8) = o1;
}

// ---------------------------------------------------------------------------
// Kernel 2: MFMA projection. BM=64, BN=192(all), BK=64, 512 thr = 8 waves.
// Outputs: qg[m][64], kg[m][64] row-major; V transposed via LDS -> vtg[b][d][s].
// ---------------------------------------------------------------------------
__global__ __launch_bounds__(512) void proj_mfma(
    const float* __restrict__ x, const short* __restrict__ Wt,
    short* __restrict__ qg, short* __restrict__ kg, short* __restrict__ vtg) {
    __shared__ short xL[64][72];
    __shared__ short wL[192][72];
    __shared__ short vL[64][72];    // [d][mlocal] transposed V tile
    int t = threadIdx.x;
    int m0 = blockIdx.x * 64;
    int w = t >> 6, l = t & 63;
    int wr = w >> 2, wc = w & 3;
    int ll = l & 15, lg = l >> 4;

    f32x4 acc[2][3] = {};

    int arow = wr * 32 + ll;
    int brow = wc * 48 + ll;
    int kcol = lg * 8;

    for (int k0 = 0; k0 < EMB; k0 += 64) {
        __syncthreads();
        {   // stage x tile 64x64: f32 -> bf16
            int row = t >> 3, c8 = (t & 7) * 8;
            const float* src = x + (long)(m0 + row) * EMB + k0 + c8;
            f32x4 a = *(const f32x4*)(src);
            f32x4 b = *(const f32x4*)(src + 4);
            short8 v;
            #pragma unroll
            for (int j = 0; j < 4; ++j) { v[j] = f2bf(a[j]); v[4 + j] = f2bf(b[j]); }
            *(short8*)(&xL[row][c8]) = v;
        }
        #pragma unroll
        for (int c = 0; c < 3; ++c) {   // stage W tile 192x64
            int idx = c * 512 + t;
            int n = idx >> 3, c8 = idx & 7;
            short8 v = *(const short8*)(Wt + (long)n * EMB + k0 + c8 * 8);
            *(short8*)(&wL[n][c8 * 8]) = v;
        }
        __syncthreads();
        #pragma unroll
        for (int ks = 0; ks < 2; ++ks) {
            short8 af[2], bf[3];
            #pragma unroll
            for (int mi = 0; mi < 2; ++mi)
                af[mi] = *(const short8*)(&xL[arow + mi * 16][kcol + ks * 32]);
            #pragma unroll
            for (int ni = 0; ni < 3; ++ni)
                bf[ni] = *(const short8*)(&wL[brow + ni * 16][kcol + ks * 32]);
            #pragma unroll
            for (int mi = 0; mi < 2; ++mi)
                #pragma unroll
                for (int ni = 0; ni < 3; ++ni)
                    acc[mi][ni] = __builtin_amdgcn_mfma_f32_16x16x32_bf16(
                        af[mi], bf[ni], acc[mi][ni], 0, 0, 0);
        }
    }
    // epilogue: C/D layout col = lane&15, row = (lane>>4)*4 + reg
    int b  = m0 >> 11;          // batch
    int s0 = m0 & 2047;         // seq offset within batch
    #pragma unroll
    for (int mi = 0; mi < 2; ++mi)
        #pragma unroll
        for (int ni = 0; ni < 3; ++ni) {
            int c = wc * 48 + ni * 16 + ll;
            int mloc = wr * 32 + mi * 16 + lg * 4;
            #pragma unroll
            for (int r = 0; r < 4; ++r) {
                short val = f2bf(acc[mi][ni][r]);
                if (c < 64)
                    qg[(long)(m0 + mloc + r) * HD + c] = val;
                else if (c < 128)
                    kg[(long)(m0 + mloc + r) * HD + (c - 64)] = val;
                else
                    vL[c - 128][mloc + r] = val;   // stride-72 rows: conflict-free
            }
        }
    __syncthreads();
    {   // cooperative coalesced store of transposed V: vtg[b][d][s0..s0+63]
        int d = t >> 3, seg = (t & 7) * 8;
        short8 vv = *(const short8*)(&vL[d][seg]);
        *(short8*)(vtg + ((long)b * HD + d) * SEQ + s0 + seg) = vv;
    }
}

// ---------------------------------------------------------------------------
// Kernel 3: MFMA causal flash attention, 1 wave/block, QBLK=16, no barriers,
// K/V fragments loaded directly from global (L2-resident). f32 out [B,S,D].
// ---------------------------------------------------------------------------
__global__ __launch_bounds__(64) void attn_mfma(
    const short* __restrict__ qg, const short* __restrict__ kg,
    const short* __restrict__ vtg, float* __restrict__ out) {
    __shared__ short PL[16][72];    // wave-local P round-trip

    int b = blockIdx.y;
    int qt = (SEQ / 16 - 1) - blockIdx.x;   // heavy tiles first
    int q0 = qt * 16;
    int l = threadIdx.x;
    int ll = l & 15, lg = l >> 4;

    const short* qb = qg + (long)b * SEQ * HD;
    const short* kb = kg + (long)b * SEQ * HD;
    const short* vb = vtg + (long)b * HD * SEQ;

    short8 qf[2];
    #pragma unroll
    for (int ks = 0; ks < 2; ++ks)
        qf[ks] = *(const short8*)(qb + (long)(q0 + ll) * HD + ks * 32 + lg * 8);

    f32x4 accO[4] = {};
    float mrow[4], lrow[4];
    #pragma unroll
    for (int r = 0; r < 4; ++r) { mrow[r] = -1e30f; lrow[r] = 0.f; }

    const float cs = 0.125f * 1.44269504088896f;
    int nkv = q0 / 64 + 1;

    for (int kt = 0; kt < nkv; ++kt) {
        int kv0 = kt * 64;

        // S = Q K^T  (K B-frags direct from global: 16 rows x 64B sectors)
        f32x4 s[4] = {};
        #pragma unroll
        for (int ks = 0; ks < 2; ++ks)
            #pragma unroll
            for (int n = 0; n < 4; ++n) {
                short8 kf = *(const short8*)(kb + (long)(kv0 + n * 16 + ll) * HD + ks * 32 + lg * 8);
                s[n] = __builtin_amdgcn_mfma_f32_16x16x32_bf16(qf[ks], kf, s[n], 0, 0, 0);
            }

        // scale + causal mask + online softmax (row = lg*4+r, col = n*16+ll)
        bool need_mask = (kv0 + 63) > q0;
        int qrow_base = q0 + lg * 4;
        float sm[4][4], tmax[4];
        #pragma unroll
        for (int r = 0; r < 4; ++r) tmax[r] = -1e30f;
        #pragma unroll
        for (int n = 0; n < 4; ++n) {
            int kvcol = kv0 + n * 16 + ll;
            #pragma unroll
            for (int r = 0; r < 4; ++r) {
                float v = s[n][r] * cs;
                if (need_mask && (kvcol > qrow_base + r)) v = -1e30f;
                sm[n][r] = v;
                tmax[r] = fmaxf(tmax[r], v);
            }
        }
        #pragma unroll
        for (int off = 1; off < 16; off <<= 1)
            #pragma unroll
            for (int r = 0; r < 4; ++r)
                tmax[r] = fmaxf(tmax[r], __shfl_xor(tmax[r], off, 64));

        float fac[4], psum[4];
        #pragma unroll
        for (int r = 0; r < 4; ++r) {
            float mnew = fmaxf(mrow[r], tmax[r]);
            fac[r] = __builtin_amdgcn_exp2f(mrow[r] - mnew);
            mrow[r] = mnew;
            psum[r] = 0.f;
        }
        #pragma unroll
        for (int n = 0; n < 4; ++n)
            #pragma unroll
            for (int r = 0; r < 4; ++r) {
                float p = __builtin_amdgcn_exp2f(sm[n][r] - mrow[r]);
                sm[n][r] = p;
                psum[r] += p;
            }
        #pragma unroll
        for (int off = 1; off < 16; off <<= 1)
            #pragma unroll
            for (int r = 0; r < 4; ++r)
                psum[r] += __shfl_xor(psum[r], off, 64);
        #pragma unroll
        for (int r = 0; r < 4; ++r) lrow[r] = lrow[r] * fac[r] + psum[r];
        #pragma unroll
        for (int n = 0; n < 4; ++n)
            #pragma unroll
            for (int r = 0; r < 4; ++r) accO[n][r] *= fac[r];

        // P -> LDS (same-wave, in-order) then PV with V^T direct from global
        #pragma unroll
        for (int n = 0; n < 4; ++n)
            #pragma unroll
            for (int r = 0; r < 4; ++r)
                PL[lg * 4 + r][n * 16 + ll] = f2bf(sm[n][r]);

        #pragma unroll
        for (int ks = 0; ks < 2; ++ks) {
            short8 pf = *(const short8*)(&PL[ll][ks * 32 + lg * 8]);
            #pragma unroll
            for (int nd = 0; nd < 4; ++nd) {
                short8 vf = *(const short8*)(vb + (long)(nd * 16 + ll) * SEQ + kv0 + ks * 32 + lg * 8);
                accO[nd] = __builtin_amdgcn_mfma_f32_16x16x32_bf16(pf, vf, accO[nd], 0, 0, 0);
            }
        }
    }

    // epilogue: f32 out [B,S,D]
    #pragma unroll
    for (int r = 0; r < 4; ++r) {
        float inv = 1.0f / lrow[r];
        #pragma unroll
        for (int nd = 0; nd < 4; ++nd)
            out[(long)b * SEQ * HD + (long)(q0 + lg * 4 + r) * HD + nd * 16 + ll]
                = accO[nd][r] * inv;
    }
}

// ---------------------------------------------------------------------------
extern "C" void kernel_launch(void* const* d_in, const int* in_sizes, int n_in,
                              void* d_out, int out_size, void* d_ws, size_t ws_size,
                              hipStream_t stream) {
    const float* x  = (const float*)d_in[0];
    const float* Wq = (const float*)d_in[1];
    const float* Wk = (const float*)d_in[2];
    const float* Wv = (const float*)d_in[3];
    float* outp = (float*)d_out;

    short* Wt  = (short*)d_ws;                                  // 384 KB
    short* qg  = (short*)((char*)d_ws + 393216);                // 2 MB
    short* kg  = (short*)((char*)d_ws + 393216 + 2097152);      // 2 MB
    short* vtg = (short*)((char*)d_ws + 393216 + 2 * 2097152);  // 2 MB

    transpose_w<<<48, 256, 0, stream>>>(Wq, Wk, Wv, Wt);
    proj_mfma<<<BATCH * SEQ / 64, 512, 0, stream>>>(x, Wt, qg, kg, vtg);
    dim3 ag(SEQ / 16, BATCH);
    attn_mfma<<<ag, 64, 0, stream>>>(qg, kg, vtg, outp);
}

// Round 20
// 102.434 us; speedup vs baseline: 10.9151x; 1.4072x over previous
//
#include <hip/hip_runtime.h>

// ROUND 20: intra-block KV-split (4 waves share one q-tile, flash-merge in
// LDS). Fixes r19's TLP deficit (occupancy 5.5%, 1 wave/SIMD): 4096 waves,
// 4/SIMD, tail 33->9 iterations. Attention reads K/V direct from L2 (r19),
// V pre-transposed by proj. Contract (r17): f32 in dict-order, W [1024][64]
// k-major, causal/S per batch, scale 1/8, f32 out [B,S,D].
// ws: Wt 384KB | qg 2MB | kg 2MB | vtg[8][64][2048] 2MB = 6.4 MB.

#define BATCH 8
#define SEQ   2048
#define EMB   1024
#define HD    64
#define QBLK  16
#define NSPL  4

typedef __attribute__((ext_vector_type(8))) short short8;
typedef __attribute__((ext_vector_type(4))) float f32x4;

static __device__ __forceinline__ short f2bf(float f) {
    union { float f; unsigned int i; } c;
    c.f = f;
    unsigned int r = c.i + 0x7fff + ((c.i >> 16) & 1);  // RNE
    return (short)(r >> 16);
}

// ---------------------------------------------------------------------------
// Kernel 1: transpose+convert Wq|Wk|Wv f32[1024][64] -> Wt bf16[192][1024]
// ---------------------------------------------------------------------------
__global__ __launch_bounds__(256) void transpose_w(
    const float* __restrict__ Wq, const float* __restrict__ Wk,
    const float* __restrict__ Wv, short* __restrict__ Wt) {
    __shared__ short tileT[64][72];
    int bid = blockIdx.x;
    int p = bid >> 4, kt = bid & 15;
    const float* W = (p == 0) ? Wq : ((p == 1) ? Wk : Wv);
    int t = threadIdx.x;
    int k0 = kt * 64;
    int row = t >> 2, c0 = (t & 3) * 16;
    const float* src = W + (long)(k0 + row) * HD + c0;
    #pragma unroll
    for (int j = 0; j < 16; ++j)
        tileT[c0 + j][row] = f2bf(src[j]);
    __syncthreads();
    int n = t >> 2, ks = (t & 3) * 16;
    short8 o0 = *(const short8*)(&tileT[n][ks]);
    short8 o1 = *(const short8*)(&tileT[n][ks + 8]);
    *(short8*)(Wt + (long)(p * 64 + n) * EMB + k0 + ks)     = o0;
    *(short8*)(Wt + (long)(p * 64 + n) * EMB + k0 + ks + 8) = o1;
}

// ---------------------------------------------------------------------------
// Kernel 2: MFMA projection (r19, unchanged). qg/kg row-major, vtg transposed.
// ---------------------------------------------------------------------------
__global__ __launch_bounds__(512) void proj_mfma(
    const float* __restrict__ x, const short* __restrict__ Wt,
    short* __restrict__ qg, short* __restrict__ kg, short* __restrict__ vtg) {
    __shared__ short xL[64][72];
    __shared__ short wL[192][72];
    __shared__ short vL[64][72];
    int t = threadIdx.x;
    int m0 = blockIdx.x * 64;
    int w = t >> 6, l = t & 63;
    int wr = w >> 2, wc = w & 3;
    int ll = l & 15, lg = l >> 4;

    f32x4 acc[2][3] = {};

    int arow = wr * 32 + ll;
    int brow = wc * 48 + ll;
    int kcol = lg * 8;

    for (int k0 = 0; k0 < EMB; k0 += 64) {
        __syncthreads();
        {
            int row = t >> 3, c8 = (t & 7) * 8;
            const float* src = x + (long)(m0 + row) * EMB + k0 + c8;
            f32x4 a = *(const f32x4*)(src);
            f32x4 b = *(const f32x4*)(src + 4);
            short8 v;
            #pragma unroll
            for (int j = 0; j < 4; ++j) { v[j] = f2bf(a[j]); v[4 + j] = f2bf(b[j]); }
            *(short8*)(&xL[row][c8]) = v;
        }
        #pragma unroll
        for (int c = 0; c < 3; ++c) {
            int idx = c * 512 + t;
            int n = idx >> 3, c8 = idx & 7;
            short8 v = *(const short8*)(Wt + (long)n * EMB + k0 + c8 * 8);
            *(short8*)(&wL[n][c8 * 8]) = v;
        }
        __syncthreads();
        #pragma unroll
        for (int ks = 0; ks < 2; ++ks) {
            short8 af[2], bf[3];
            #pragma unroll
            for (int mi = 0; mi < 2; ++mi)
                af[mi] = *(const short8*)(&xL[arow + mi * 16][kcol + ks * 32]);
            #pragma unroll
            for (int ni = 0; ni < 3; ++ni)
                bf[ni] = *(const short8*)(&wL[brow + ni * 16][kcol + ks * 32]);
            #pragma unroll
            for (int mi = 0; mi < 2; ++mi)
                #pragma unroll
                for (int ni = 0; ni < 3; ++ni)
                    acc[mi][ni] = __builtin_amdgcn_mfma_f32_16x16x32_bf16(
                        af[mi], bf[ni], acc[mi][ni], 0, 0, 0);
        }
    }
    int b  = m0 >> 11;
    int s0 = m0 & 2047;
    #pragma unroll
    for (int mi = 0; mi < 2; ++mi)
        #pragma unroll
        for (int ni = 0; ni < 3; ++ni) {
            int c = wc * 48 + ni * 16 + ll;
            int mloc = wr * 32 + mi * 16 + lg * 4;
            #pragma unroll
            for (int r = 0; r < 4; ++r) {
                short val = f2bf(acc[mi][ni][r]);
                if (c < 64)
                    qg[(long)(m0 + mloc + r) * HD + c] = val;
                else if (c < 128)
                    kg[(long)(m0 + mloc + r) * HD + (c - 64)] = val;
                else
                    vL[c - 128][mloc + r] = val;
            }
        }
    __syncthreads();
    {
        int d = t >> 3, seg = (t & 7) * 8;
        short8 vv = *(const short8*)(&vL[d][seg]);
        *(short8*)(vtg + ((long)b * HD + d) * SEQ + s0 + seg) = vv;
    }
}

// ---------------------------------------------------------------------------
// Kernel 3: attention, 4-wave KV-split per q-tile + LDS flash-merge.
// grid (128, 8) x 256 thr. K/V direct from global (L2). f32 out [B,S,D].
// ---------------------------------------------------------------------------
__global__ __launch_bounds__(256, 4) void attn_mfma(
    const short* __restrict__ qg, const short* __restrict__ kg,
    const short* __restrict__ vtg, float* __restrict__ out) {
    __shared__ float pO[NSPL][16][65];   // partial O (padded: merge reads 2-way)
    __shared__ float pM[NSPL][16];
    __shared__ float pLs[NSPL][16];
    __shared__ short PL[NSPL][16][72];   // per-wave P round-trip

    int b = blockIdx.y;
    int qt = (SEQ / QBLK - 1) - blockIdx.x;
    int q0 = qt * QBLK;
    int t = threadIdx.x;
    int w = t >> 6, l = t & 63;
    int ll = l & 15, lg = l >> 4;

    const short* qb = qg + (long)b * SEQ * HD;
    const short* kb = kg + (long)b * SEQ * HD;
    const short* vb = vtg + (long)b * HD * SEQ;

    short8 qf[2];
    #pragma unroll
    for (int ks = 0; ks < 2; ++ks)
        qf[ks] = *(const short8*)(qb + (long)(q0 + ll) * HD + ks * 32 + lg * 8);

    f32x4 accO[4] = {};
    float mrow[4], lrow[4];
    #pragma unroll
    for (int r = 0; r < 4; ++r) { mrow[r] = -1e30f; lrow[r] = 0.f; }

    const float cs = 0.125f * 1.44269504088896f;
    int nkv = q0 / 64 + 1;

    for (int kt = w; kt < nkv; kt += NSPL) {
        int kv0 = kt * 64;

        // S = Q K^T (K frags direct from global)
        f32x4 s[4] = {};
        #pragma unroll
        for (int ks = 0; ks < 2; ++ks)
            #pragma unroll
            for (int n = 0; n < 4; ++n) {
                short8 kf = *(const short8*)(kb + (long)(kv0 + n * 16 + ll) * HD + ks * 32 + lg * 8);
                s[n] = __builtin_amdgcn_mfma_f32_16x16x32_bf16(qf[ks], kf, s[n], 0, 0, 0);
            }

        // scale + causal mask + online softmax (row = lg*4+r, col = n*16+ll)
        bool need_mask = (kv0 + 63) > q0;
        int qrow_base = q0 + lg * 4;
        float sm[4][4], tmax[4];
        #pragma unroll
        for (int r = 0; r < 4; ++r) tmax[r] = -1e30f;
        #pragma unroll
        for (int n = 0; n < 4; ++n) {
            int kvcol = kv0 + n * 16 + ll;
            #pragma unroll
            for (int r = 0; r < 4; ++r) {
                float v = s[n][r] * cs;
                if (need_mask && (kvcol > qrow_base + r)) v = -1e30f;
                sm[n][r] = v;
                tmax[r] = fmaxf(tmax[r], v);
            }
        }
        #pragma unroll
        for (int off = 1; off < 16; off <<= 1)
            #pragma unroll
            for (int r = 0; r < 4; ++r)
                tmax[r] = fmaxf(tmax[r], __shfl_xor(tmax[r], off, 64));

        float fac[4], psum[4];
        #pragma unroll
        for (int r = 0; r < 4; ++r) {
            float mnew = fmaxf(mrow[r], tmax[r]);
            fac[r] = __builtin_amdgcn_exp2f(mrow[r] - mnew);
            mrow[r] = mnew;
            psum[r] = 0.f;
        }
        #pragma unroll
        for (int n = 0; n < 4; ++n)
            #pragma unroll
            for (int r = 0; r < 4; ++r) {
                float p = __builtin_amdgcn_exp2f(sm[n][r] - mrow[r]);
                sm[n][r] = p;
                psum[r] += p;
            }
        #pragma unroll
        for (int off = 1; off < 16; off <<= 1)
            #pragma unroll
            for (int r = 0; r < 4; ++r)
                psum[r] += __shfl_xor(psum[r], off, 64);
        #pragma unroll
        for (int r = 0; r < 4; ++r) lrow[r] = lrow[r] * fac[r] + psum[r];
        #pragma unroll
        for (int n = 0; n < 4; ++n)
            #pragma unroll
            for (int r = 0; r < 4; ++r) accO[n][r] *= fac[r];

        // P -> LDS (same-wave) then PV with V^T direct from global
        #pragma unroll
        for (int n = 0; n < 4; ++n)
            #pragma unroll
            for (int r = 0; r < 4; ++r)
                PL[w][lg * 4 + r][n * 16 + ll] = f2bf(sm[n][r]);

        #pragma unroll
        for (int ks = 0; ks < 2; ++ks) {
            short8 pf = *(const short8*)(&PL[w][ll][ks * 32 + lg * 8]);
            #pragma unroll
            for (int nd = 0; nd < 4; ++nd) {
                short8 vf = *(const short8*)(vb + (long)(nd * 16 + ll) * SEQ + kv0 + ks * 32 + lg * 8);
                accO[nd] = __builtin_amdgcn_mfma_f32_16x16x32_bf16(pf, vf, accO[nd], 0, 0, 0);
            }
        }
    }

    // write partials (C/D layout: row q = lg*4+r, col d = nd*16+ll)
    #pragma unroll
    for (int nd = 0; nd < 4; ++nd)
        #pragma unroll
        for (int r = 0; r < 4; ++r)
            pO[w][lg * 4 + r][nd * 16 + ll] = accO[nd][r];
    if (ll == 0) {
        #pragma unroll
        for (int r = 0; r < 4; ++r) {
            pM[w][lg * 4 + r]  = mrow[r];
            pLs[w][lg * 4 + r] = lrow[r];
        }
    }
    __syncthreads();

    // flash-merge 4 partials: thread t -> q = t>>4, d0 = (t&15)*4
    {
        int q = t >> 4, d0 = (t & 15) * 4;
        float M = pM[0][q];
        #pragma unroll
        for (int w2 = 1; w2 < NSPL; ++w2) M = fmaxf(M, pM[w2][q]);
        float L = 0.f;
        float o0 = 0.f, o1 = 0.f, o2 = 0.f, o3 = 0.f;
        #pragma unroll
        for (int w2 = 0; w2 < NSPL; ++w2) {
            float sc = __builtin_amdgcn_exp2f(pM[w2][q] - M);
            L += pLs[w2][q] * sc;
            o0 += sc * pO[w2][q][d0];
            o1 += sc * pO[w2][q][d0 + 1];
            o2 += sc * pO[w2][q][d0 + 2];
            o3 += sc * pO[w2][q][d0 + 3];
        }
        float inv = 1.0f / L;
        float* dst = out + (long)b * SEQ * HD + (long)(q0 + q) * HD + d0;
        dst[0] = o0 * inv; dst[1] = o1 * inv; dst[2] = o2 * inv; dst[3] = o3 * inv;
    }
}

// ---------------------------------------------------------------------------
extern "C" void kernel_launch(void* const* d_in, const int* in_sizes, int n_in,
                              void* d_out, int out_size, void* d_ws, size_t ws_size,
                              hipStream_t stream) {
    const float* x  = (const float*)d_in[0];
    const float* Wq = (const float*)d_in[1];
    const float* Wk = (const float*)d_in[2];
    const float* Wv = (const float*)d_in[3];
    float* outp = (float*)d_out;

    short* Wt  = (short*)d_ws;                                  // 384 KB
    short* qg  = (short*)((char*)d_ws + 393216);                // 2 MB
    short* kg  = (short*)((char*)d_ws + 393216 + 2097152);      // 2 MB
    short* vtg = (short*)((char*)d_ws + 393216 + 2 * 2097152);  // 2 MB

    transpose_w<<<48, 256, 0, stream>>>(Wq, Wk, Wv, Wt);
    proj_mfma<<<BATCH * SEQ / 64, 512, 0, stream>>>(x, Wt, qg, kg, vtg);
    dim3 ag(SEQ / QBLK, BATCH);
    attn_mfma<<<ag, 256, 0, stream>>>(qg, kg, vtg, outp);
}